// Round 1
// baseline (131.225 us; speedup 1.0000x reference)
//
#include <hip/hip_runtime.h>

#define L2_REG 0.01f
#define CHUNK 2048

// Stage a 2048-element i-chunk (y_i, exp(r_i)) in LDS; each thread owns one j
// and accumulates num_j = sum exp(r_i)*[y_i >= y_j], den_j = sum [y_i >= y_j].
__global__ __launch_bounds__(256) void cox_partial(const float* __restrict__ rp,
                                                   const float* __restrict__ y,
                                                   float* __restrict__ ws_num,
                                                   float* __restrict__ ws_den,
                                                   int njt) {
    __shared__ float ls_y[CHUNK];
    __shared__ float ls_er[CHUNK];
    const int jt    = blockIdx.x % njt;
    const int chunk = blockIdx.x / njt;
    const int tid   = threadIdx.x;
    const long ibase = (long)chunk * CHUNK;

    // Cooperative staging: 256 threads x 2 float4 loads = 2048 elements.
#pragma unroll
    for (int k = 0; k < 2; ++k) {
        const int idx = (k * 256 + tid) * 4;
        float4 yv = *reinterpret_cast<const float4*>(y + ibase + idx);
        float4 rv = *reinterpret_cast<const float4*>(rp + ibase + idx);
        *reinterpret_cast<float4*>(&ls_y[idx]) = yv;
        float4 ev;
        ev.x = __expf(rv.x); ev.y = __expf(rv.y);
        ev.z = __expf(rv.z); ev.w = __expf(rv.w);
        *reinterpret_cast<float4*>(&ls_er[idx]) = ev;
    }
    __syncthreads();

    const int j = jt * 256 + tid;
    const float yj = y[j];
    float num = 0.f, den = 0.f;
#pragma unroll 4
    for (int ii = 0; ii < CHUNK; ii += 4) {
        float4 y4 = *reinterpret_cast<float4*>(&ls_y[ii]);   // LDS broadcast
        float4 e4 = *reinterpret_cast<float4*>(&ls_er[ii]);
        num += (y4.x >= yj) ? e4.x : 0.f;  den += (y4.x >= yj) ? 1.f : 0.f;
        num += (y4.y >= yj) ? e4.y : 0.f;  den += (y4.y >= yj) ? 1.f : 0.f;
        num += (y4.z >= yj) ? e4.z : 0.f;  den += (y4.z >= yj) ? 1.f : 0.f;
        num += (y4.w >= yj) ? e4.w : 0.f;  den += (y4.w >= yj) ? 1.f : 0.f;
    }
    atomicAdd(&ws_num[j], num);
    atomicAdd(&ws_den[j], den);
}

__global__ __launch_bounds__(256) void cox_finalize(const float* __restrict__ rp,
                                                    const int* __restrict__ e,
                                                    const float* __restrict__ ws_num,
                                                    const float* __restrict__ ws_den,
                                                    float* __restrict__ ws_acc) {
    __shared__ float l1[4];
    __shared__ float l2[4];
    const int j = blockIdx.x * 256 + threadIdx.x;
    const float num = ws_num[j];
    const float den = ws_den[j];
    const float ef  = (float)e[j];
    float term = (rp[j] - __logf(num / den)) * ef;
    float es = ef;
#pragma unroll
    for (int off = 32; off; off >>= 1) {
        term += __shfl_down(term, off, 64);
        es   += __shfl_down(es,   off, 64);
    }
    const int lane = threadIdx.x & 63, wave = threadIdx.x >> 6;
    if (lane == 0) { l1[wave] = term; l2[wave] = es; }
    __syncthreads();
    if (threadIdx.x == 0) {
        atomicAdd(&ws_acc[0], l1[0] + l1[1] + l1[2] + l1[3]);
        atomicAdd(&ws_acc[1], l2[0] + l2[1] + l2[2] + l2[3]);
    }
}

__global__ __launch_bounds__(256) void cox_combine(const float* __restrict__ W, int wn,
                                                   const float* __restrict__ ws_acc,
                                                   float* __restrict__ out) {
    __shared__ float l[4];
    float s = 0.f;
    const float4* W4 = reinterpret_cast<const float4*>(W);
    const int n4 = wn >> 2;
    for (int i = threadIdx.x; i < n4; i += 256) {
        float4 w = W4[i];
        s = fmaf(w.x, w.x, s); s = fmaf(w.y, w.y, s);
        s = fmaf(w.z, w.z, s); s = fmaf(w.w, w.w, s);
    }
#pragma unroll
    for (int off = 32; off; off >>= 1) s += __shfl_down(s, off, 64);
    const int lane = threadIdx.x & 63, wave = threadIdx.x >> 6;
    if (lane == 0) l[wave] = s;
    __syncthreads();
    if (threadIdx.x == 0) {
        const float w2 = l[0] + l[1] + l[2] + l[3];
        out[0] = -ws_acc[0] / ws_acc[1] + L2_REG * sqrtf(w2);
    }
}

extern "C" void kernel_launch(void* const* d_in, const int* in_sizes, int n_in,
                              void* d_out, int out_size, void* d_ws, size_t ws_size,
                              hipStream_t stream) {
    const float* rp = (const float*)d_in[0];
    const float* y  = (const float*)d_in[1];
    const int*   e  = (const int*)d_in[2];
    const float* W  = (const float*)d_in[3];
    const int n  = in_sizes[0];   // 16384
    const int wn = in_sizes[3];   // 131072

    float* ws_num = (float*)d_ws;
    float* ws_den = ws_num + n;
    float* ws_acc = ws_den + n;   // [0]=sum_terms, [1]=sum_e

    hipMemsetAsync(d_ws, 0, (size_t)(2 * n + 2) * sizeof(float), stream);

    const int njt    = n / 256;    // 64 j-tiles
    const int nchunk = n / CHUNK;  // 8 i-chunks
    cox_partial<<<dim3(njt * nchunk), dim3(256), 0, stream>>>(rp, y, ws_num, ws_den, njt);
    cox_finalize<<<dim3(njt), dim3(256), 0, stream>>>(rp, e, ws_num, ws_den, ws_acc);
    cox_combine<<<dim3(1), dim3(256), 0, stream>>>(W, wn, ws_acc, (float*)d_out);
}

// Round 2
// 106.982 us; speedup vs baseline: 1.2266x; 1.2266x over previous
//
#include <hip/hip_runtime.h>

#define L2_REG 0.01f
#define NJT 64       // j tiles of 256
#define NCHUNK 16    // i chunks
#define CHUNK 1024   // elements per i chunk

// K0: blocks [0,64): er[i] = exp(rp[i]) (one elem/thread).
//     blocks [64,128): ||W||^2 partial over 2048 floats -> atomicAdd acc[2].
__global__ __launch_bounds__(256) void cox_prep(const float* __restrict__ rp,
                                                const float* __restrict__ W,
                                                float* __restrict__ er,
                                                float* __restrict__ acc) {
    const int b = blockIdx.x;
    if (b < 64) {
        const int i = b * 256 + threadIdx.x;
        er[i] = __expf(rp[i]);
    } else {
        __shared__ float l[4];
        const float4* W4 = reinterpret_cast<const float4*>(W) + (b - 64) * 512;
        float s = 0.f;
#pragma unroll
        for (int k = 0; k < 2; ++k) {
            float4 w = W4[k * 256 + threadIdx.x];
            s = fmaf(w.x, w.x, s); s = fmaf(w.y, w.y, s);
            s = fmaf(w.z, w.z, s); s = fmaf(w.w, w.w, s);
        }
#pragma unroll
        for (int off = 32; off; off >>= 1) s += __shfl_down(s, off, 64);
        const int lane = threadIdx.x & 63, wave = threadIdx.x >> 6;
        if (lane == 0) l[wave] = s;
        __syncthreads();
        if (threadIdx.x == 0) atomicAdd(&acc[2], l[0] + l[1] + l[2] + l[3]);
    }
}

// K1: each thread owns one j; scans a 1024-element i-chunk with WAVE-UNIFORM
// (scalar) loads of y[i], er[i] — no LDS, no syncthreads. 64 jt x 16 chunks.
__global__ __launch_bounds__(256) void cox_partial(const float* __restrict__ er,
                                                   const float* __restrict__ y,
                                                   float* __restrict__ ws_num,
                                                   float* __restrict__ ws_den) {
    const int jt    = blockIdx.x & (NJT - 1);
    const int chunk = blockIdx.x >> 6;
    const int j = jt * 256 + threadIdx.x;
    const float yj = y[j];
    // Uniform base pointers: every lane reads the same address each iteration
    // -> compiler should emit s_load_dwordx4 (scalar pipe), zero LDS traffic.
    const float4* __restrict__ y4 = reinterpret_cast<const float4*>(y  + chunk * CHUNK);
    const float4* __restrict__ e4 = reinterpret_cast<const float4*>(er + chunk * CHUNK);
    float num = 0.f, den = 0.f;
#pragma unroll 4
    for (int i = 0; i < CHUNK / 4; ++i) {
        const float4 yv = y4[i];
        const float4 ev = e4[i];
        num += (yv.x >= yj) ? ev.x : 0.f;  den += (yv.x >= yj) ? 1.f : 0.f;
        num += (yv.y >= yj) ? ev.y : 0.f;  den += (yv.y >= yj) ? 1.f : 0.f;
        num += (yv.z >= yj) ? ev.z : 0.f;  den += (yv.z >= yj) ? 1.f : 0.f;
        num += (yv.w >= yj) ? ev.w : 0.f;  den += (yv.w >= yj) ? 1.f : 0.f;
    }
    atomicAdd(&ws_num[j], num);
    atomicAdd(&ws_den[j], den);
}

// K2: per-j term + block reduce -> atomic scalar accumulators.
__global__ __launch_bounds__(256) void cox_finalize(const float* __restrict__ rp,
                                                    const int* __restrict__ e,
                                                    const float* __restrict__ ws_num,
                                                    const float* __restrict__ ws_den,
                                                    float* __restrict__ acc) {
    __shared__ float l1[4];
    __shared__ float l2[4];
    const int j = blockIdx.x * 256 + threadIdx.x;
    const float ef = (float)e[j];
    float term = (rp[j] - __logf(ws_num[j] / ws_den[j])) * ef;
    float es = ef;
#pragma unroll
    for (int off = 32; off; off >>= 1) {
        term += __shfl_down(term, off, 64);
        es   += __shfl_down(es,   off, 64);
    }
    const int lane = threadIdx.x & 63, wave = threadIdx.x >> 6;
    if (lane == 0) { l1[wave] = term; l2[wave] = es; }
    __syncthreads();
    if (threadIdx.x == 0) {
        atomicAdd(&acc[0], l1[0] + l1[1] + l1[2] + l1[3]);
        atomicAdd(&acc[1], l2[0] + l2[1] + l2[2] + l2[3]);
    }
}

// K3: final scalar.
__global__ void cox_final(const float* __restrict__ acc, float* __restrict__ out) {
    if (threadIdx.x == 0)
        out[0] = -acc[0] / acc[1] + L2_REG * sqrtf(acc[2]);
}

extern "C" void kernel_launch(void* const* d_in, const int* in_sizes, int n_in,
                              void* d_out, int out_size, void* d_ws, size_t ws_size,
                              hipStream_t stream) {
    const float* rp = (const float*)d_in[0];
    const float* y  = (const float*)d_in[1];
    const int*   e  = (const int*)d_in[2];
    const float* W  = (const float*)d_in[3];
    const int n = in_sizes[0];   // 16384

    float* ws_num = (float*)d_ws;          // [n]
    float* ws_den = ws_num + n;            // [n]
    float* acc    = ws_den + n;            // [3]: terms, sum_e, w2
    float* er     = acc + 4;               // [n] (no zeroing needed)

    // Zero ws_num/ws_den/acc only.
    hipMemsetAsync(d_ws, 0, (size_t)(2 * n + 4) * sizeof(float), stream);

    cox_prep<<<dim3(128), dim3(256), 0, stream>>>(rp, W, er, acc);
    cox_partial<<<dim3(NJT * NCHUNK), dim3(256), 0, stream>>>(er, y, ws_num, ws_den);
    cox_finalize<<<dim3(NJT), dim3(256), 0, stream>>>(rp, e, ws_num, ws_den, acc);
    cox_final<<<dim3(1), dim3(64), 0, stream>>>(acc, (float*)d_out);
}